// Round 16
// baseline (558.751 us; speedup 1.0000x reference)
//
#include <hip/hip_runtime.h>
#include <hip/hip_bf16.h>
#include <math.h>

#define N_NODES 100000
#define N_EDGES 1600000
#define DIM 64
#define N_GRAPHS 256
#define BN_EPS 1e-5f
#define N_XCD 8
#define BUCKET ((N_NODES + N_XCD - 1) / N_XCD)                    // 12500
#define FILL_CHUNKS 128
#define FILL_ESIZE ((N_EDGES + FILL_CHUNKS - 1) / FILL_CHUNKS)    // 12500
#define CSR_STRIDE 48   // max in-degree ~35 (Poisson 16, 100K draws); 48 = ~8 sigma
#define HIST_BLOCKS (FILL_CHUNKS * N_XCD)                          // 1024
#define GEMM0_BLOCKS 1024
#define QS ((size_t)N_NODES * 16)    // shorts per column-quarter array

__device__ inline unsigned short f2bf(float f) {
    __hip_bfloat16 h = __float2bfloat16(f);   // RNE
    return *reinterpret_cast<unsigned short*>(&h);
}
__device__ inline unsigned int pack2bf(float a, float b) {
    return (unsigned int)f2bf(a) | ((unsigned int)f2bf(b) << 16);
}
__device__ inline float bf_lo(unsigned int u) { return __uint_as_float(u << 16); }
__device__ inline float bf_hi(unsigned int u) { return __uint_as_float(u & 0xffff0000u); }

// ---- fat kernel: CSR build (blocks 0..1023, XCD-bucketed) co-resident with
//      layer-1 GEMM (blocks 1024..2047, unscaled t = bf16(x @ W0), quarter cols).
__global__ __launch_bounds__(256) void hist_gemm0(const int* __restrict__ src,
                                                  const int* __restrict__ dst,
                                                  int* __restrict__ cnt,
                                                  int* __restrict__ csr_pad,
                                                  const float* __restrict__ x,
                                                  const float* __restrict__ W,
                                                  unsigned short* __restrict__ tbq) {
    if (blockIdx.x < HIST_BLOCKS) {
        int chunk = blockIdx.x >> 3;
        int lo = (blockIdx.x & (N_XCD - 1)) * BUCKET;
        int e0 = chunk * FILL_ESIZE;
        int e1 = min(e0 + FILL_ESIZE, N_EDGES);
        for (int e = e0 + threadIdx.x; e < e1; e += 256) {
            int d = __builtin_nontemporal_load(&dst[e]);
            if ((unsigned)(d - lo) < (unsigned)BUCKET) {
                int r = atomicAdd(&cnt[d], 1);
                csr_pad[d * CSR_STRIDE + r] = __builtin_nontemporal_load(&src[e]);
            }
        }
    } else {
        int tid = threadIdx.x;
        int d = tid & 63;
        int wv = tid >> 6;
        float wcol[64];
        #pragma unroll
        for (int k = 0; k < 64; ++k) wcol[k] = W[k * 64 + d];
        unsigned short* tdst = tbq + (size_t)(d >> 4) * QS + (d & 15);
        int gb = blockIdx.x - HIST_BLOCKS;
        int nwaves = GEMM0_BLOCKS * 4;
        for (int row = gb * 4 + wv; row < N_NODES; row += nwaves) {
            int urow = __builtin_amdgcn_readfirstlane(row);
            const float* hr = x + (size_t)urow * 64;
            float a0 = 0.f, a1 = 0.f, a2 = 0.f, a3 = 0.f;
            #pragma unroll
            for (int k = 0; k < 64; k += 4) {
                a0 = fmaf(hr[k + 0], wcol[k + 0], a0);
                a1 = fmaf(hr[k + 1], wcol[k + 1], a1);
                a2 = fmaf(hr[k + 2], wcol[k + 2], a2);
                a3 = fmaf(hr[k + 3], wcol[k + 3], a3);
            }
            float acc = (a0 + a1) + (a2 + a3);
            tdst[(size_t)urow * 16] = f2bf(acc);   // unscaled; finish_scale applies dinv
        }
    }
}

// ---- finish: dinv[row] = rsqrt(cnt+1); all 4 tb quarters *= dinv (in place) ----
__global__ __launch_bounds__(256) void finish_scale(const int* __restrict__ cnt,
                                                    unsigned short* __restrict__ tbq,
                                                    float* __restrict__ dinv) {
    const int total = N_NODES * 2;   // uint4 (8 bf16) groups per quarter
    for (int j = blockIdx.x * 256 + threadIdx.x; j < total; j += gridDim.x * 256) {
        int row = j >> 1;
        float di = rsqrtf((float)(cnt[row] + 1));
        #pragma unroll
        for (int q = 0; q < 4; ++q) {
            unsigned short* p = tbq + (size_t)q * QS + (size_t)j * 8;
            uint4 u = *reinterpret_cast<const uint4*>(p);
            uint4 o;
            o.x = pack2bf(bf_lo(u.x) * di, bf_hi(u.x) * di);
            o.y = pack2bf(bf_lo(u.y) * di, bf_hi(u.y) * di);
            o.z = pack2bf(bf_lo(u.z) * di, bf_hi(u.z) * di);
            o.w = pack2bf(bf_lo(u.w) * di, bf_hi(u.w) * di);
            *reinterpret_cast<uint4*>(p) = o;
        }
        if ((j & 1) == 0) dinv[row] = di;
    }
}

// ---- fused BN+ReLU+GEMM (layers 2/3), quarter-column layout, prefetch-pipelined ----
__global__ __launch_bounds__(256) void bn_gemm_v(const unsigned short* __restrict__ aggq,
                                                 const float* __restrict__ stats,
                                                 const float* __restrict__ gamma,
                                                 const float* __restrict__ beta,
                                                 const float* __restrict__ W,
                                                 const float* __restrict__ dinv,
                                                 unsigned short* __restrict__ tbq) {
    __shared__ float abuf[4][64];
    __shared__ float scale_s[64], shift_s[64];
    int tid = threadIdx.x;
    int d = tid & 63;
    int wv = tid >> 6;
    if (tid < 64) {
        const float inv_n = 1.0f / (float)N_NODES;
        float mean = stats[tid] * inv_n;
        float var = fmaxf(stats[64 + tid] * inv_n - mean * mean, 0.f);
        float rs = rsqrtf(var + BN_EPS) * gamma[tid];
        scale_s[tid] = rs;
        shift_s[tid] = beta[tid] - mean * rs;
    }
    float wcol[64];
    #pragma unroll
    for (int k = 0; k < 64; ++k) wcol[k] = W[k * 64 + d];
    __syncthreads();
    float sc = scale_s[d], sh = shift_s[d];
    const unsigned short* hsrc = aggq + (size_t)(d >> 4) * QS + (d & 15);
    unsigned short* tdst = tbq + (size_t)(d >> 4) * QS + (d & 15);
    const float4* av = reinterpret_cast<const float4*>(abuf[wv]);
    int nwaves = gridDim.x * 4;
    int row = blockIdx.x * 4 + wv;
    unsigned short hraw = 0;
    if (row < N_NODES) hraw = hsrc[(size_t)row * 16];
    while (row < N_NODES) {
        int nrow = row + nwaves;
        unsigned short hnraw = 0;
        if (nrow < N_NODES) hnraw = hsrc[(size_t)nrow * 16];   // prefetch next row
        float di = dinv[row];
        float h = __uint_as_float(((unsigned int)hraw) << 16);
        float a = fmaxf(fmaf(h, sc, sh), 0.f);
        abuf[wv][d] = a;   // wave-private: lgkmcnt ordering, no barrier needed
        float a0 = 0.f, a1 = 0.f, a2 = 0.f, a3 = 0.f;
        #pragma unroll
        for (int k4 = 0; k4 < 16; ++k4) {
            float4 v = av[k4];
            int k = k4 * 4;
            a0 = fmaf(v.x, wcol[k + 0], a0);
            a1 = fmaf(v.y, wcol[k + 1], a1);
            a2 = fmaf(v.z, wcol[k + 2], a2);
            a3 = fmaf(v.w, wcol[k + 3], a3);
        }
        float acc = (a0 + a1) + (a2 + a3);
        tdst[(size_t)row * 16] = f2bf(acc * di);
        row = nrow;
        hraw = hnraw;
    }
}

// ------- quarter-column CSR gather: XCD pair {2q,2q+1} owns quarter q
//         (3.2 MB, L2-resident -> row reads become L2 hits).
//         16 groups x 4 lanes x uint2(4 cols); 1 idx instr + 1 row instr
//         per 16 edges. -------
__global__ __launch_bounds__(256) void gather_agg(const int* __restrict__ csr_pad,
                                                  const int* __restrict__ cnt,
                                                  const float* __restrict__ dinv,
                                                  const unsigned short* __restrict__ tbq,
                                                  const float* __restrict__ bias,
                                                  unsigned short* __restrict__ aggq,
                                                  float* __restrict__ stats) {
    int tid = threadIdx.x;
    int wave = tid >> 6;
    int lane = tid & 63;
    int o    = lane >> 2;        // group 0..15 -> edge slot
    int c    = lane & 3;         // cols c*4 .. c*4+3 within this quarter

    int g8  = blockIdx.x & 7;    // -> XCD
    int q   = g8 >> 1;           // quarter owned by this XCD pair
    int sub = g8 & 1;            // which node half within the pair
    int hbid = blockIdx.x >> 3;  // 0..255
    const unsigned short* tbH = tbq + (size_t)q * QS;
    unsigned short*      aggH = aggq + (size_t)q * QS;
    const float*          biH = bias + q * 16;

    float4 s4  = {0.f, 0.f, 0.f, 0.f};
    float4 sq4 = {0.f, 0.f, 0.f, 0.f};

    for (int v = ((hbid << 1) | sub) * 4 + wave; v < N_NODES; v += 2048) {
        int beg = v * CSR_STRIDE;
        int end = beg + cnt[v];
        float4 A = {0.f, 0.f, 0.f, 0.f};
        int e = beg;
        for (; e + 16 <= end; e += 16) {
            int s0 = __builtin_nontemporal_load(&csr_pad[e + o]);
            uint2 u0 = *reinterpret_cast<const uint2*>(tbH + (size_t)s0 * 16 + c * 4);
            A.x += bf_lo(u0.x); A.y += bf_hi(u0.x);
            A.z += bf_lo(u0.y); A.w += bf_hi(u0.y);
        }
        int rem = end - e;
        if (o < rem) {
            int s0 = __builtin_nontemporal_load(&csr_pad[e + o]);
            uint2 u0 = *reinterpret_cast<const uint2*>(tbH + (size_t)s0 * 16 + c * 4);
            A.x += bf_lo(u0.x); A.y += bf_hi(u0.x);
            A.z += bf_lo(u0.y); A.w += bf_hi(u0.y);
        }

        // butterfly across the 16 groups (lanes ^4, ^8, ^16, ^32)
        A.x += __shfl_xor(A.x, 4, 64); A.x += __shfl_xor(A.x, 8, 64);
        A.x += __shfl_xor(A.x, 16, 64); A.x += __shfl_xor(A.x, 32, 64);
        A.y += __shfl_xor(A.y, 4, 64); A.y += __shfl_xor(A.y, 8, 64);
        A.y += __shfl_xor(A.y, 16, 64); A.y += __shfl_xor(A.y, 32, 64);
        A.z += __shfl_xor(A.z, 4, 64); A.z += __shfl_xor(A.z, 8, 64);
        A.z += __shfl_xor(A.z, 16, 64); A.z += __shfl_xor(A.z, 32, 64);
        A.w += __shfl_xor(A.w, 4, 64); A.w += __shfl_xor(A.w, 8, 64);
        A.w += __shfl_xor(A.w, 16, 64); A.w += __shfl_xor(A.w, 32, 64);

        if (o == 0) {   // lanes 0..3, lane == c
            float di = dinv[v];
            uint2 uv = *reinterpret_cast<const uint2*>(tbH + (size_t)v * 16 + c * 4);
            float4 bi = *reinterpret_cast<const float4*>(biH + c * 4);
            float4 val;
            val.x = fmaf(di, A.x + bf_lo(uv.x), bi.x);
            val.y = fmaf(di, A.y + bf_hi(uv.x), bi.y);
            val.z = fmaf(di, A.z + bf_lo(uv.y), bi.z);
            val.w = fmaf(di, A.w + bf_hi(uv.y), bi.w);
            uint2 ov;
            ov.x = pack2bf(val.x, val.y);
            ov.y = pack2bf(val.z, val.w);
            *reinterpret_cast<uint2*>(aggH + (size_t)v * 16 + c * 4) = ov;
            s4.x += val.x; s4.y += val.y; s4.z += val.z; s4.w += val.w;
            sq4.x += val.x * val.x; sq4.y += val.y * val.y;
            sq4.z += val.z * val.z; sq4.w += val.w * val.w;
        }
    }

    __shared__ float shs[4][16];
    __shared__ float shq[4][16];
    if (o == 0) {
        *reinterpret_cast<float4*>(&shs[wave][c * 4]) = s4;
        *reinterpret_cast<float4*>(&shq[wave][c * 4]) = sq4;
    }
    __syncthreads();
    if (tid < 16) {
        float S = shs[0][tid] + shs[1][tid] + shs[2][tid] + shs[3][tid];
        float Q = shq[0][tid] + shq[1][tid] + shq[2][tid] + shq[3][tid];
        unsafeAtomicAdd(&stats[q * 16 + tid], S);
        unsafeAtomicAdd(&stats[64 + q * 16 + tid], Q);
    }
}

// ---------------- pool stage 1: partial mean/max per (graph, quarter), inline BN ----------------
__global__ __launch_bounds__(256) void pool_partial(const unsigned short* __restrict__ aggq,
                                                    const int* __restrict__ batch,
                                                    const float* __restrict__ stats,
                                                    const float* __restrict__ gamma,
                                                    const float* __restrict__ beta,
                                                    float* __restrict__ pS,
                                                    float* __restrict__ pM) {
    int bid = blockIdx.x;
    int g = bid >> 2, p = bid & 3;
    __shared__ float scale[64], shift[64];
    __shared__ int bounds[2];
    int tid = threadIdx.x;
    if (tid < 64) {
        const float inv_n = 1.0f / (float)N_NODES;
        float mean = stats[tid] * inv_n;
        float var = fmaxf(stats[64 + tid] * inv_n - mean * mean, 0.f);
        float rs = rsqrtf(var + BN_EPS) * gamma[tid];
        scale[tid] = rs;
        shift[tid] = beta[tid] - mean * rs;
    }
    if (tid < 2) {
        int target = g + tid;
        int lo = 0, hi = N_NODES;
        while (lo < hi) {
            int mid = (lo + hi) >> 1;
            if (batch[mid] < target) lo = mid + 1; else hi = mid;
        }
        bounds[tid] = lo;
    }
    __syncthreads();
    int lo = bounds[0], hi = bounds[1];
    int d = tid & 63, g4 = tid >> 6;
    const unsigned short* hsrc = aggq + (size_t)(d >> 4) * QS + (d & 15);
    float sc = scale[d], sh = shift[d];
    float s = 0.f, m = -3.402823466e38f;
    for (int row = lo + p * 4 + g4; row < hi; row += 16) {
        float v = __uint_as_float(((unsigned int)hsrc[(size_t)row * 16]) << 16);
        v = fmaf(v, sc, sh);
        s += v;
        m = fmaxf(m, v);
    }
    __shared__ float shs[8][64];
    shs[g4][d] = s;
    shs[4 + g4][d] = m;
    __syncthreads();
    if (tid < 64) {
        float S = shs[0][tid] + shs[1][tid] + shs[2][tid] + shs[3][tid];
        float M = fmaxf(fmaxf(shs[4][tid], shs[5][tid]), fmaxf(shs[6][tid], shs[7][tid]));
        pS[bid * 64 + tid] = S;
        pM[bid * 64 + tid] = M;
    }
}

// ---------------- pool stage 2: combine 4 partials per graph ----------------
__global__ __launch_bounds__(64) void pool_final(const int* __restrict__ batch,
                                                 const float* __restrict__ pS,
                                                 const float* __restrict__ pM,
                                                 float* __restrict__ out) {
    int g = blockIdx.x, d = threadIdx.x;
    __shared__ int bounds[2];
    if (d < 2) {
        int target = g + d;
        int lo = 0, hi = N_NODES;
        while (lo < hi) {
            int mid = (lo + hi) >> 1;
            if (batch[mid] < target) lo = mid + 1; else hi = mid;
        }
        bounds[d] = lo;
    }
    __syncthreads();
    int cnt = bounds[1] - bounds[0];
    int base = g * 4 * 64 + d;
    float S = (pS[base] + pS[base + 64]) + (pS[base + 128] + pS[base + 192]);
    float M = fmaxf(fmaxf(pM[base], pM[base + 64]), fmaxf(pM[base + 128], pM[base + 192]));
    float mean = S / fmaxf((float)cnt, 1.0f);
    out[g * 64 + d] = (cnt > 0) ? (mean + M) : 0.0f;
}

extern "C" void kernel_launch(void* const* d_in, const int* in_sizes, int n_in,
                              void* d_out, int out_size, void* d_ws, size_t ws_size,
                              hipStream_t stream) {
    const float* x     = (const float*)d_in[0];
    const int*   eidx  = (const int*)d_in[1];
    const int*   batch = (const int*)d_in[2];
    const float* W[3]  = {(const float*)d_in[3], (const float*)d_in[7],  (const float*)d_in[11]};
    const float* b[3]  = {(const float*)d_in[4], (const float*)d_in[8],  (const float*)d_in[12]};
    const float* gm[3] = {(const float*)d_in[5], (const float*)d_in[9],  (const float*)d_in[13]};
    const float* be[3] = {(const float*)d_in[6], (const float*)d_in[10], (const float*)d_in[14]};

    unsigned short* tbq   = (unsigned short*)d_ws;                      // 4 x N*16 bf16 = 12.8 MB
    unsigned short* aggq  = tbq + 4 * QS;                               // 4 x N*16 bf16 = 12.8 MB
    float* dinv     = (float*)(aggq + 4 * QS);                          // N
    float* stats    = dinv + N_NODES;                                   // 3*128
    int*   cnt      = (int*)(stats + 384);                              // N  (adjacent: 1 memset)
    float* poolS    = (float*)(cnt + N_NODES);                          // 1024*64
    float* poolM    = poolS + 1024 * 64;                                // 1024*64
    int*   csr_pad  = (int*)(poolM + 1024 * 64);                        // N*48  19.2 MB

    const int* srcp = eidx;
    const int* dstp = eidx + N_EDGES;

    // one memset: stats (3*128 floats) + cnt (N ints), contiguous
    hipMemsetAsync(stats, 0, (384 + N_NODES) * sizeof(float), stream);

    // fat kernel: CSR build (latency-bound) co-resident with layer-1 GEMM
    hist_gemm0<<<HIST_BLOCKS + GEMM0_BLOCKS, 256, 0, stream>>>(srcp, dstp, cnt, csr_pad,
                                                               x, W[0], tbq);
    // dinv + in-place dinv scaling of all tb quarters
    finish_scale<<<1024, 256, 0, stream>>>(cnt, tbq, dinv);

    // layer 1 aggregation (quarter-column, XCD-pair-resident)
    gather_agg<<<2048, 256, 0, stream>>>(csr_pad, cnt, dinv, tbq, b[0], aggq, stats);

    // layer 2: fused BN+ReLU+GEMM, then aggregation
    bn_gemm_v<<<1024, 256, 0, stream>>>(aggq, stats, gm[0], be[0], W[1], dinv, tbq);
    gather_agg<<<2048, 256, 0, stream>>>(csr_pad, cnt, dinv, tbq, b[1], aggq, stats + 128);

    // layer 3
    bn_gemm_v<<<1024, 256, 0, stream>>>(aggq, stats + 128, gm[1], be[1], W[2], dinv, tbq);
    gather_agg<<<2048, 256, 0, stream>>>(csr_pad, cnt, dinv, tbq, b[2], aggq, stats + 256);

    // pool with inline BN3 (two-stage)
    pool_partial<<<N_GRAPHS * 4, 256, 0, stream>>>(aggq, batch, stats + 256, gm[2], be[2], poolS, poolM);
    pool_final<<<N_GRAPHS, 64, 0, stream>>>(batch, poolS, poolM, (float*)d_out);
}

// Round 17
// 425.445 us; speedup vs baseline: 1.3133x; 1.3133x over previous
//
#include <hip/hip_runtime.h>
#include <hip/hip_bf16.h>
#include <math.h>

#define N_NODES 100000
#define N_EDGES 1600000
#define DIM 64
#define N_GRAPHS 256
#define BN_EPS 1e-5f
#define N_XCD 8
#define BUCKET ((N_NODES + N_XCD - 1) / N_XCD)                    // 12500
#define FILL_CHUNKS 128
#define FILL_ESIZE ((N_EDGES + FILL_CHUNKS - 1) / FILL_CHUNKS)    // 12500
#define CSR_STRIDE 48   // max in-degree ~35 (Poisson 16, 100K draws); 48 = ~8 sigma
#define HIST_BLOCKS (FILL_CHUNKS * N_XCD)                          // 1024
#define GEMM0_BLOCKS 1024

__device__ inline unsigned short f2bf(float f) {
    __hip_bfloat16 h = __float2bfloat16(f);   // RNE
    return *reinterpret_cast<unsigned short*>(&h);
}
__device__ inline unsigned int pack2bf(float a, float b) {
    return (unsigned int)f2bf(a) | ((unsigned int)f2bf(b) << 16);
}
__device__ inline float bf_lo(unsigned int u) { return __uint_as_float(u << 16); }
__device__ inline float bf_hi(unsigned int u) { return __uint_as_float(u & 0xffff0000u); }

// ---- fat kernel: CSR build (blocks 0..1023, XCD-bucketed) co-resident with
//      layer-1 GEMM (blocks 1024..2047, unscaled t = bf16(x @ W0), split cols).
__global__ __launch_bounds__(256) void hist_gemm0(const int* __restrict__ src,
                                                  const int* __restrict__ dst,
                                                  int* __restrict__ cnt,
                                                  int* __restrict__ csr_pad,
                                                  const float* __restrict__ x,
                                                  const float* __restrict__ W,
                                                  unsigned short* __restrict__ tbA,
                                                  unsigned short* __restrict__ tbB) {
    if (blockIdx.x < HIST_BLOCKS) {
        int chunk = blockIdx.x >> 3;
        int lo = (blockIdx.x & (N_XCD - 1)) * BUCKET;
        int e0 = chunk * FILL_ESIZE;
        int e1 = min(e0 + FILL_ESIZE, N_EDGES);
        for (int e = e0 + threadIdx.x; e < e1; e += 256) {
            int d = __builtin_nontemporal_load(&dst[e]);
            if ((unsigned)(d - lo) < (unsigned)BUCKET) {
                int r = atomicAdd(&cnt[d], 1);
                csr_pad[d * CSR_STRIDE + r] = __builtin_nontemporal_load(&src[e]);
            }
        }
    } else {
        int tid = threadIdx.x;
        int d = tid & 63;
        int wv = tid >> 6;
        float wcol[64];
        #pragma unroll
        for (int k = 0; k < 64; ++k) wcol[k] = W[k * 64 + d];
        unsigned short* tdst = (d < 32) ? (tbA + d) : (tbB + (d - 32));
        int gb = blockIdx.x - HIST_BLOCKS;
        int nwaves = GEMM0_BLOCKS * 4;
        for (int row = gb * 4 + wv; row < N_NODES; row += nwaves) {
            int urow = __builtin_amdgcn_readfirstlane(row);
            const float* hr = x + (size_t)urow * 64;
            float a0 = 0.f, a1 = 0.f, a2 = 0.f, a3 = 0.f;
            #pragma unroll
            for (int k = 0; k < 64; k += 4) {
                a0 = fmaf(hr[k + 0], wcol[k + 0], a0);
                a1 = fmaf(hr[k + 1], wcol[k + 1], a1);
                a2 = fmaf(hr[k + 2], wcol[k + 2], a2);
                a3 = fmaf(hr[k + 3], wcol[k + 3], a3);
            }
            float acc = (a0 + a1) + (a2 + a3);
            tdst[(size_t)urow * 32] = f2bf(acc);   // unscaled; finish_scale applies dinv
        }
    }
}

// ---- finish: dinv[row] = rsqrt(cnt+1); tbA/tbB rows *= dinv (in place) ----
__global__ __launch_bounds__(256) void finish_scale(const int* __restrict__ cnt,
                                                    unsigned short* __restrict__ tbA,
                                                    unsigned short* __restrict__ tbB,
                                                    float* __restrict__ dinv) {
    const int per_arr = N_NODES * 4;   // uint4 (8 bf16) groups per array (32 cols = 4 groups)
    for (int i = blockIdx.x * 256 + threadIdx.x; i < 2 * per_arr; i += gridDim.x * 256) {
        int second = (i >= per_arr);
        int j = second ? (i - per_arr) : i;
        int row = j >> 2;
        float di = rsqrtf((float)(cnt[row] + 1));
        unsigned short* p = (second ? tbB : tbA) + (size_t)j * 8;
        uint4 u = *reinterpret_cast<const uint4*>(p);
        uint4 o;
        o.x = pack2bf(bf_lo(u.x) * di, bf_hi(u.x) * di);
        o.y = pack2bf(bf_lo(u.y) * di, bf_hi(u.y) * di);
        o.z = pack2bf(bf_lo(u.z) * di, bf_hi(u.z) * di);
        o.w = pack2bf(bf_lo(u.w) * di, bf_hi(u.w) * di);
        *reinterpret_cast<uint4*>(p) = o;
        if (!second && (j & 3) == 0) dinv[row] = di;
    }
}

// ---- fused BN+ReLU+GEMM (layers 2/3), split-column layout, prefetch-pipelined ----
__global__ __launch_bounds__(256) void bn_gemm_v(const unsigned short* __restrict__ aggA,
                                                 const unsigned short* __restrict__ aggB,
                                                 const float* __restrict__ stats,
                                                 const float* __restrict__ gamma,
                                                 const float* __restrict__ beta,
                                                 const float* __restrict__ W,
                                                 const float* __restrict__ dinv,
                                                 unsigned short* __restrict__ tbA,
                                                 unsigned short* __restrict__ tbB) {
    __shared__ float abuf[4][64];
    __shared__ float scale_s[64], shift_s[64];
    int tid = threadIdx.x;
    int d = tid & 63;
    int wv = tid >> 6;
    if (tid < 64) {
        const float inv_n = 1.0f / (float)N_NODES;
        float mean = stats[tid] * inv_n;
        float var = fmaxf(stats[64 + tid] * inv_n - mean * mean, 0.f);
        float rs = rsqrtf(var + BN_EPS) * gamma[tid];
        scale_s[tid] = rs;
        shift_s[tid] = beta[tid] - mean * rs;
    }
    float wcol[64];
    #pragma unroll
    for (int k = 0; k < 64; ++k) wcol[k] = W[k * 64 + d];
    __syncthreads();
    float sc = scale_s[d], sh = shift_s[d];
    const unsigned short* hsrc = (d < 32) ? (aggA + d) : (aggB + (d - 32));
    unsigned short* tdst = (d < 32) ? (tbA + d) : (tbB + (d - 32));
    const float4* av = reinterpret_cast<const float4*>(abuf[wv]);
    int nwaves = gridDim.x * 4;
    int row = blockIdx.x * 4 + wv;
    unsigned short hraw = 0;
    if (row < N_NODES) hraw = hsrc[(size_t)row * 32];
    while (row < N_NODES) {
        int nrow = row + nwaves;
        unsigned short hnraw = 0;
        if (nrow < N_NODES) hnraw = hsrc[(size_t)nrow * 32];   // prefetch next row
        float di = dinv[row];
        float h = __uint_as_float(((unsigned int)hraw) << 16);
        float a = fmaxf(fmaf(h, sc, sh), 0.f);
        abuf[wv][d] = a;   // wave-private: lgkmcnt ordering, no barrier needed
        float a0 = 0.f, a1 = 0.f, a2 = 0.f, a3 = 0.f;
        #pragma unroll
        for (int k4 = 0; k4 < 16; ++k4) {
            float4 v = av[k4];
            int k = k4 * 4;
            a0 = fmaf(v.x, wcol[k + 0], a0);
            a1 = fmaf(v.y, wcol[k + 1], a1);
            a2 = fmaf(v.z, wcol[k + 2], a2);
            a3 = fmaf(v.w, wcol[k + 3], a3);
        }
        float acc = (a0 + a1) + (a2 + a3);
        tdst[(size_t)row * 32] = f2bf(acc * di);
        row = nrow;
        hraw = hnraw;
    }
}

// ------- half-column CSR gather: blocks on XCDs 0-3 do cols 0-31 (tbA only),
//         XCDs 4-7 do cols 32-63 (tbB only). Per-XCD working set halves ->
//         row FETCH 88 -> ~44 MB. 8 groups x 8 lanes x uint2(4 cols). -------
__global__ __launch_bounds__(256) void gather_agg(const int* __restrict__ csr_pad,
                                                  const int* __restrict__ cnt,
                                                  const float* __restrict__ dinv,
                                                  const unsigned short* __restrict__ tbA,
                                                  const unsigned short* __restrict__ tbB,
                                                  const float* __restrict__ bias,
                                                  unsigned short* __restrict__ aggA,
                                                  unsigned short* __restrict__ aggB,
                                                  float* __restrict__ stats) {
    int tid = threadIdx.x;
    int wave = tid >> 6;
    int lane = tid & 63;
    int o    = lane >> 3;        // group 0..7 -> edge slot
    int c    = lane & 7;         // cols c*4 .. c*4+3 within this half

    int g8   = blockIdx.x & 7;
    int half = (g8 >= 4) ? 1 : 0;
    int hbid = (blockIdx.x >> 3) * 4 + (g8 & 3);   // 0..1023 within half
    const unsigned short* tbH  = half ? tbB : tbA;
    unsigned short*       aggH = half ? aggB : aggA;
    const float*          biH  = bias + half * 32;

    float4 s4  = {0.f, 0.f, 0.f, 0.f};
    float4 sq4 = {0.f, 0.f, 0.f, 0.f};

    for (int v = hbid * 4 + wave; v < N_NODES; v += 4096) {
        int beg = v * CSR_STRIDE;
        int end = beg + cnt[v];
        float4 A = {0,0,0,0}, B = {0,0,0,0};
        int e = beg;
        for (; e + 16 <= end; e += 16) {
            int s0 = csr_pad[e + o];
            int s1 = csr_pad[e + 8 + o];
            uint2 u0 = *reinterpret_cast<const uint2*>(tbH + (size_t)s0 * 32 + c * 4);
            uint2 u1 = *reinterpret_cast<const uint2*>(tbH + (size_t)s1 * 32 + c * 4);
            A.x += bf_lo(u0.x); A.y += bf_hi(u0.x); A.z += bf_lo(u0.y); A.w += bf_hi(u0.y);
            B.x += bf_lo(u1.x); B.y += bf_hi(u1.x); B.z += bf_lo(u1.y); B.w += bf_hi(u1.y);
        }
        for (; e + o < end; e += 8) {
            int s0 = csr_pad[e + o];
            uint2 u0 = *reinterpret_cast<const uint2*>(tbH + (size_t)s0 * 32 + c * 4);
            A.x += bf_lo(u0.x); A.y += bf_hi(u0.x); A.z += bf_lo(u0.y); A.w += bf_hi(u0.y);
        }
        A.x += B.x; A.y += B.y; A.z += B.z; A.w += B.w;

        // butterfly over the 8 groups (lanes ^8, ^16, ^32)
        A.x += __shfl_xor(A.x, 8, 64); A.x += __shfl_xor(A.x, 16, 64); A.x += __shfl_xor(A.x, 32, 64);
        A.y += __shfl_xor(A.y, 8, 64); A.y += __shfl_xor(A.y, 16, 64); A.y += __shfl_xor(A.y, 32, 64);
        A.z += __shfl_xor(A.z, 8, 64); A.z += __shfl_xor(A.z, 16, 64); A.z += __shfl_xor(A.z, 32, 64);
        A.w += __shfl_xor(A.w, 8, 64); A.w += __shfl_xor(A.w, 16, 64); A.w += __shfl_xor(A.w, 32, 64);

        if (o == 0) {   // lanes 0..7, lane == c
            float di = dinv[v];
            uint2 uv = *reinterpret_cast<const uint2*>(tbH + (size_t)v * 32 + c * 4);
            float4 bi = *reinterpret_cast<const float4*>(biH + c * 4);
            float4 val;
            val.x = fmaf(di, A.x + bf_lo(uv.x), bi.x);
            val.y = fmaf(di, A.y + bf_hi(uv.x), bi.y);
            val.z = fmaf(di, A.z + bf_lo(uv.y), bi.z);
            val.w = fmaf(di, A.w + bf_hi(uv.y), bi.w);
            uint2 ov;
            ov.x = pack2bf(val.x, val.y);
            ov.y = pack2bf(val.z, val.w);
            *reinterpret_cast<uint2*>(aggH + (size_t)v * 32 + c * 4) = ov;
            s4.x += val.x; s4.y += val.y; s4.z += val.z; s4.w += val.w;
            sq4.x += val.x * val.x; sq4.y += val.y * val.y;
            sq4.z += val.z * val.z; sq4.w += val.w * val.w;
        }
    }

    __shared__ float shs[4][32];
    __shared__ float shq[4][32];
    if (o == 0) {
        *reinterpret_cast<float4*>(&shs[wave][c * 4]) = s4;
        *reinterpret_cast<float4*>(&shq[wave][c * 4]) = sq4;
    }
    __syncthreads();
    if (tid < 32) {
        float S = shs[0][tid] + shs[1][tid] + shs[2][tid] + shs[3][tid];
        float Q = shq[0][tid] + shq[1][tid] + shq[2][tid] + shq[3][tid];
        unsafeAtomicAdd(&stats[half * 32 + tid], S);
        unsafeAtomicAdd(&stats[64 + half * 32 + tid], Q);
    }
}

// ---------------- pool stage 1: partial mean/max per (graph, quarter), inline BN ----------------
__global__ __launch_bounds__(256) void pool_partial(const unsigned short* __restrict__ aggA,
                                                    const unsigned short* __restrict__ aggB,
                                                    const int* __restrict__ batch,
                                                    const float* __restrict__ stats,
                                                    const float* __restrict__ gamma,
                                                    const float* __restrict__ beta,
                                                    float* __restrict__ pS,
                                                    float* __restrict__ pM) {
    int bid = blockIdx.x;
    int g = bid >> 2, p = bid & 3;
    __shared__ float scale[64], shift[64];
    __shared__ int bounds[2];
    int tid = threadIdx.x;
    if (tid < 64) {
        const float inv_n = 1.0f / (float)N_NODES;
        float mean = stats[tid] * inv_n;
        float var = fmaxf(stats[64 + tid] * inv_n - mean * mean, 0.f);
        float rs = rsqrtf(var + BN_EPS) * gamma[tid];
        scale[tid] = rs;
        shift[tid] = beta[tid] - mean * rs;
    }
    if (tid < 2) {
        int target = g + tid;
        int lo = 0, hi = N_NODES;
        while (lo < hi) {
            int mid = (lo + hi) >> 1;
            if (batch[mid] < target) lo = mid + 1; else hi = mid;
        }
        bounds[tid] = lo;
    }
    __syncthreads();
    int lo = bounds[0], hi = bounds[1];
    int d = tid & 63, g4 = tid >> 6;
    const unsigned short* hsrc = (d < 32) ? (aggA + d) : (aggB + (d - 32));
    float sc = scale[d], sh = shift[d];
    float s = 0.f, m = -3.402823466e38f;
    for (int row = lo + p * 4 + g4; row < hi; row += 16) {
        float v = __uint_as_float(((unsigned int)hsrc[(size_t)row * 32]) << 16);
        v = fmaf(v, sc, sh);
        s += v;
        m = fmaxf(m, v);
    }
    __shared__ float shs[8][64];
    shs[g4][d] = s;
    shs[4 + g4][d] = m;
    __syncthreads();
    if (tid < 64) {
        float S = shs[0][tid] + shs[1][tid] + shs[2][tid] + shs[3][tid];
        float M = fmaxf(fmaxf(shs[4][tid], shs[5][tid]), fmaxf(shs[6][tid], shs[7][tid]));
        pS[bid * 64 + tid] = S;
        pM[bid * 64 + tid] = M;
    }
}

// ---------------- pool stage 2: combine 4 partials per graph ----------------
__global__ __launch_bounds__(64) void pool_final(const int* __restrict__ batch,
                                                 const float* __restrict__ pS,
                                                 const float* __restrict__ pM,
                                                 float* __restrict__ out) {
    int g = blockIdx.x, d = threadIdx.x;
    __shared__ int bounds[2];
    if (d < 2) {
        int target = g + d;
        int lo = 0, hi = N_NODES;
        while (lo < hi) {
            int mid = (lo + hi) >> 1;
            if (batch[mid] < target) lo = mid + 1; else hi = mid;
        }
        bounds[d] = lo;
    }
    __syncthreads();
    int cnt = bounds[1] - bounds[0];
    int base = g * 4 * 64 + d;
    float S = (pS[base] + pS[base + 64]) + (pS[base + 128] + pS[base + 192]);
    float M = fmaxf(fmaxf(pM[base], pM[base + 64]), fmaxf(pM[base + 128], pM[base + 192]));
    float mean = S / fmaxf((float)cnt, 1.0f);
    out[g * 64 + d] = (cnt > 0) ? (mean + M) : 0.0f;
}

extern "C" void kernel_launch(void* const* d_in, const int* in_sizes, int n_in,
                              void* d_out, int out_size, void* d_ws, size_t ws_size,
                              hipStream_t stream) {
    const float* x     = (const float*)d_in[0];
    const int*   eidx  = (const int*)d_in[1];
    const int*   batch = (const int*)d_in[2];
    const float* W[3]  = {(const float*)d_in[3], (const float*)d_in[7],  (const float*)d_in[11]};
    const float* b[3]  = {(const float*)d_in[4], (const float*)d_in[8],  (const float*)d_in[12]};
    const float* gm[3] = {(const float*)d_in[5], (const float*)d_in[9],  (const float*)d_in[13]};
    const float* be[3] = {(const float*)d_in[6], (const float*)d_in[10], (const float*)d_in[14]};

    unsigned short* tbA   = (unsigned short*)d_ws;                      // N*32 bf16 6.4 MB
    unsigned short* tbB   = tbA + (size_t)N_NODES * 32;                 // N*32
    unsigned short* aggA  = tbB + (size_t)N_NODES * 32;                 // N*32
    unsigned short* aggB  = aggA + (size_t)N_NODES * 32;                // N*32
    float* dinv     = (float*)(aggB + (size_t)N_NODES * 32);            // N
    float* stats    = dinv + N_NODES;                                   // 3*128
    int*   cnt      = (int*)(stats + 384);                              // N  (adjacent: 1 memset)
    float* poolS    = (float*)(cnt + N_NODES);                          // 1024*64
    float* poolM    = poolS + 1024 * 64;                                // 1024*64
    int*   csr_pad  = (int*)(poolM + 1024 * 64);                        // N*48  19.2 MB

    const int* srcp = eidx;
    const int* dstp = eidx + N_EDGES;

    // one memset: stats (3*128 floats) + cnt (N ints), contiguous
    hipMemsetAsync(stats, 0, (384 + N_NODES) * sizeof(float), stream);

    // fat kernel: CSR build (latency-bound) co-resident with layer-1 GEMM
    hist_gemm0<<<HIST_BLOCKS + GEMM0_BLOCKS, 256, 0, stream>>>(srcp, dstp, cnt, csr_pad,
                                                               x, W[0], tbA, tbB);
    // dinv + in-place dinv scaling of tbA/tbB
    finish_scale<<<1024, 256, 0, stream>>>(cnt, tbA, tbB, dinv);

    // layer 1 aggregation (half-column, XCD-split)
    gather_agg<<<2048, 256, 0, stream>>>(csr_pad, cnt, dinv, tbA, tbB, b[0], aggA, aggB, stats);

    // layer 2: fused BN+ReLU+GEMM, then aggregation
    bn_gemm_v<<<1024, 256, 0, stream>>>(aggA, aggB, stats, gm[0], be[0], W[1], dinv, tbA, tbB);
    gather_agg<<<2048, 256, 0, stream>>>(csr_pad, cnt, dinv, tbA, tbB, b[1], aggA, aggB, stats + 128);

    // layer 3
    bn_gemm_v<<<1024, 256, 0, stream>>>(aggA, aggB, stats + 128, gm[1], be[1], W[2], dinv, tbA, tbB);
    gather_agg<<<2048, 256, 0, stream>>>(csr_pad, cnt, dinv, tbA, tbB, b[2], aggA, aggB, stats + 256);

    // pool with inline BN3 (two-stage)
    pool_partial<<<N_GRAPHS * 4, 256, 0, stream>>>(aggA, aggB, batch, stats + 256, gm[2], be[2], poolS, poolM);
    pool_final<<<N_GRAPHS, 64, 0, stream>>>(batch, poolS, poolM, (float*)d_out);
}